// Round 6
// baseline (654.961 us; speedup 1.0000x reference)
//
#include <hip/hip_runtime.h>
#include <hip/hip_bf16.h>
#include <math.h>

typedef __attribute__((ext_vector_type(8))) short s8v;     // 8 bf16
typedef __attribute__((ext_vector_type(4))) float f32x4;   // MFMA C/D

__device__ __forceinline__ ushort f2bf(float x){ __hip_bfloat16 h = __float2bfloat16(x); return *(ushort*)&h; }
__device__ __forceinline__ float  bf2f(ushort u){ return __bfloat162float(*(__hip_bfloat16*)&u); }

// async global->LDS, 16B per lane; LDS dest = wave-uniform base + lane*16
__device__ __forceinline__ void gload16(const void* g, void* l) {
  __builtin_amdgcn_global_load_lds(
      (const __attribute__((address_space(1))) void*)g,
      (__attribute__((address_space(3))) void*)l, 16, 0, 0);
}

// K-index maps (applied at 8-element granularity; all preserve 8-contiguity)
// 0: identity   1: k&4095 (wrap: K=8192 over 4096 rows)
// 3: [Wh Wl Wh Wl] on [256][512]   4: [X X] (dup 256-col)   5: [Ah Ah Al Al] on [*][512]
template<int MAP> __device__ __forceinline__ int kmap(int k){
  if constexpr (MAP==0) return k;
  else if constexpr (MAP==1) return k & 4095;
  else if constexpr (MAP==3) return (((k>>8)&1)<<8) | (k&255);
  else if constexpr (MAP==4) return k & 255;
  else return (((k>>9)&1)<<8) | (k&255);
}

// ===================== GEMM =====================
// Operands bf16, natural layout: A[M][K], B[N][K] (K contiguous).
// FR=4: 128x128 block (wave 64x64). FR=2: 64x64 block (wave 32x32).
// Grid: blockIdx.x = N-tiles (small, co-dispatched blocks share A-tile), blockIdx.y = M-tiles.
// EPI: 0 = f32 C (+kp part offset); 1 = bf16 C; 2 = blend f32 C = aL*blend+(1-aL)*v;
//      6 = f32 C + f32 transposed C2; 7 = f32 C + bf16 transposed C2
template<int AMAP, int BMAP, int EPI, int FR>
__global__ __launch_bounds__(256)
void gemm_kernel(const ushort* __restrict__ A, int lda, long long sA,
                 const ushort* __restrict__ B, int ldb, long long sB,
                 void* __restrict__ Cp, void* __restrict__ Cp2,
                 int ldc, long long sC, int ldc2, long long sC2,
                 long long kpC, int Kloc, int kparts,
                 const float* __restrict__ blend,
                 const float* __restrict__ alpha_p, const int* __restrict__ L_p)
{
  constexpr int BMt = 32*FR;
  __shared__ ushort As[BMt][32];   // linear, global_load_lds-compatible
  __shared__ ushort Bs[BMt][32];

  const int z  = blockIdx.z;
  const int b  = z / kparts;
  const int kp = z - b*kparts;
  const int kbase = kp * Kloc;
  A += (size_t)b * sA;
  B += (size_t)b * sB;
  const int m0 = blockIdx.y * BMt;
  const int n0 = blockIdx.x * BMt;
  const int t = threadIdx.x, lane = t & 63, wid = t >> 6;
  const int wr = (wid>>1)*(16*FR), wc = (wid&1)*(16*FR);
  const int lrow = lane & 15, koff = (lane>>4)<<3;
  const int rsub = lane >> 2;          // staging row within 16-row chunk
  const int kc   = (lane & 3) * 8;     // staging k-offset (8 bf16 = 16B)

  f32x4 acc[FR][FR];
  #pragma unroll
  for (int i=0;i<FR;i++)
    #pragma unroll
    for (int j=0;j<FR;j++) acc[i][j] = (f32x4)(0.f);

  for (int k0 = 0; k0 < Kloc; k0 += 32) {
    // stage A,B via async 16B direct-to-LDS (per-lane global addr carries kmap; LDS linear)
    #pragma unroll
    for (int c = wid; c < 2*FR; c += 4) {
      const int row = c*16 + rsub;
      gload16(A + (size_t)(m0+row)*lda + kmap<AMAP>(kbase+k0+kc), (char*)&As[0][0] + c*1024);
      gload16(B + (size_t)(n0+row)*ldb + kmap<BMAP>(kbase+k0+kc), (char*)&Bs[0][0] + c*1024);
    }
    __syncthreads();
    s8v af[FR], bfv[FR];
    #pragma unroll
    for (int mi=0; mi<FR; mi++) af[mi]  = *(const s8v*)&As[wr+mi*16+lrow][koff];
    #pragma unroll
    for (int ni=0; ni<FR; ni++) bfv[ni] = *(const s8v*)&Bs[wc+ni*16+lrow][koff];
    #pragma unroll
    for (int mi=0; mi<FR; mi++)
      #pragma unroll
      for (int ni=0; ni<FR; ni++)
        acc[mi][ni] = __builtin_amdgcn_mfma_f32_16x16x32_bf16(af[mi], bfv[ni], acc[mi][ni], 0,0,0);
    __syncthreads();
  }

  float aL = 0.f;
  if constexpr (EPI==2) { aL = powf(*alpha_p, (float)(*L_p)); }
  const int cr = (lane>>4)<<2, cc = lane & 15;
  #pragma unroll
  for (int mi=0; mi<FR; mi++)
    #pragma unroll
    for (int ni=0; ni<FR; ni++) {
      const int row0 = m0 + wr + mi*16 + cr;
      const int col  = n0 + wc + ni*16 + cc;
      if constexpr (EPI==0) {
        float* C = (float*)Cp + kp*kpC + (size_t)b*sC;
        #pragma unroll
        for (int r=0;r<4;r++) C[(size_t)(row0+r)*ldc + col] = acc[mi][ni][r];
      } else if constexpr (EPI==1) {
        ushort* C = (ushort*)Cp + (size_t)b*sC;
        #pragma unroll
        for (int r=0;r<4;r++) C[(size_t)(row0+r)*ldc + col] = f2bf(acc[mi][ni][r]);
      } else if constexpr (EPI==2) {
        float* C = (float*)Cp + (size_t)b*sC;
        const float* bl = blend + (size_t)b*sC;
        #pragma unroll
        for (int r=0;r<4;r++) {
          const size_t idx = (size_t)(row0+r)*ldc + col;
          C[idx] = aL*bl[idx] + (1.f-aL)*acc[mi][ni][r];
        }
      } else if constexpr (EPI==6) {
        float* C = (float*)Cp + (size_t)b*sC;
        #pragma unroll
        for (int r=0;r<4;r++) C[(size_t)(row0+r)*ldc + col] = acc[mi][ni][r];
        float* C2 = (float*)Cp2 + (size_t)b*sC2 + (size_t)col*ldc2 + row0;
        *(f32x4*)C2 = acc[mi][ni];
      } else {  // EPI==7
        float* C = (float*)Cp + (size_t)b*sC;
        #pragma unroll
        for (int r=0;r<4;r++) C[(size_t)(row0+r)*ldc + col] = acc[mi][ni][r];
        ushort4 o;
        o.x = f2bf(acc[mi][ni][0]); o.y = f2bf(acc[mi][ni][1]);
        o.z = f2bf(acc[mi][ni][2]); o.w = f2bf(acc[mi][ni][3]);
        *(ushort4*)((ushort*)Cp2 + (size_t)b*sC2 + (size_t)col*ldc2 + row0) = o;
      }
    }
}

// ===================== transposes =====================
// inc f32 [b][4096][2048] -> incbf bf16 straight + incT bf16 [b][2048][4096]
// (+ optional direct f32 passthrough to outInc in plan A). Streaming: nontemporal.
__global__ __launch_bounds__(256)
void trans_inc_kernel(const float* __restrict__ src, float* __restrict__ outF32, int writeF32,
                      ushort* __restrict__ incbf, ushort* __restrict__ incT)
{
  __shared__ ushort T[64][65];
  const int b = blockIdx.z, m0 = blockIdx.x*64, e0 = blockIdx.y*64;
  const int t = threadIdx.x, rl = t>>2, cl = (t&3)*16;
  const size_t roff = (size_t)b*4096*2048 + (size_t)(m0+rl)*2048 + e0 + cl;
  const float* s = src + roff;
  ushort tmp[16] __attribute__((aligned(16)));
  f32x4 vv[4];
  #pragma unroll
  for (int i=0;i<4;i++) {
    vv[i] = __builtin_nontemporal_load(((const f32x4*)s) + i);
    tmp[4*i+0]=f2bf(vv[i][0]); tmp[4*i+1]=f2bf(vv[i][1]);
    tmp[4*i+2]=f2bf(vv[i][2]); tmp[4*i+3]=f2bf(vv[i][3]);
  }
  if (writeF32) {
    f32x4* o = (f32x4*)(outF32 + roff);
    #pragma unroll
    for (int i=0;i<4;i++) __builtin_nontemporal_store(vv[i], o + i);
  }
  ushort* d = incbf + roff;
  __builtin_nontemporal_store(*(s8v*)&tmp[0], (s8v*)d);
  __builtin_nontemporal_store(*(s8v*)&tmp[8], (s8v*)(d+8));
  #pragma unroll
  for (int j=0;j<16;j++) T[rl][cl+j] = tmp[j];
  __syncthreads();
  const int er = t>>2, mc = (t&3)*16;
  ushort o[16] __attribute__((aligned(16)));
  #pragma unroll
  for (int j=0;j<16;j++) o[j] = T[mc+j][er];
  ushort* d2 = incT + (size_t)b*2048*4096 + (size_t)(e0+er)*4096 + m0 + mc;
  __builtin_nontemporal_store(*(s8v*)&o[0], (s8v*)d2);
  __builtin_nontemporal_store(*(s8v*)&o[8], (s8v*)(d2+8));
}

// feat f32 [b][4096][256] -> fT bf16 [b][256][8192]: hi at col m, lo at col 4096+m
__global__ __launch_bounds__(256)
void trans_feat_kernel(const float* __restrict__ feat, ushort* __restrict__ fT)
{
  __shared__ ushort Th[64][65], Tl[64][65];
  const int b = blockIdx.z, m0 = blockIdx.x*64, d0 = blockIdx.y*64;
  const int t = threadIdx.x, rl = t>>2, cl = (t&3)*16;
  const float* s = feat + (size_t)b*4096*256 + (size_t)(m0+rl)*256 + d0 + cl;
  #pragma unroll
  for (int i=0;i<4;i++) {
    float4 v = ((const float4*)s)[i];
    float a[4] = {v.x,v.y,v.z,v.w};
    #pragma unroll
    for (int j=0;j<4;j++) {
      ushort h = f2bf(a[j]); Th[rl][cl+4*i+j] = h; Tl[rl][cl+4*i+j] = f2bf(a[j] - bf2f(h));
    }
  }
  __syncthreads();
  const int dr = t>>2, mc = (t&3)*16;
  ushort oh[16] __attribute__((aligned(16)));
  ushort ol[16] __attribute__((aligned(16)));
  #pragma unroll
  for (int j=0;j<16;j++) { oh[j] = Th[mc+j][dr]; ol[j] = Tl[mc+j][dr]; }
  ushort* d2 = fT + (size_t)b*256*8192 + (size_t)(d0+dr)*8192 + m0 + mc;
  *(s8v*)d2 = *(s8v*)&oh[0]; *(s8v*)(d2+8) = *(s8v*)&oh[8];
  *(s8v*)(d2+4096) = *(s8v*)&ol[0]; *(s8v*)(d2+4104) = *(s8v*)&ol[8];
}

// W f32 [256][256] -> Ws [256][512] = [Wh | Wl]
__global__ __launch_bounds__(256)
void cvt_w_kernel(const float4* __restrict__ W, ushort* __restrict__ Ws)
{
  size_t i  = (size_t)blockIdx.x * 256 + threadIdx.x;
  size_t e0 = i * 4;
  int c = (int)(e0 & 255), r = (int)(e0 >> 8);
  float4 v = W[i];
  float a[4] = {v.x,v.y,v.z,v.w};
  ushort* hi = Ws + (size_t)r*512 + c;
  #pragma unroll
  for (int j=0;j<4;j++) { ushort h = f2bf(a[j]); hi[j] = h; hi[256+j] = f2bf(a[j]-bf2f(h)); }
}

// sum split-K AGG parts -> AGGcat bf16 [b*2048][512] = [Ah | Al]
__global__ __launch_bounds__(256)
void aggsum_kernel(const float* __restrict__ parts, long long kpC, int kparts,
                   ushort* __restrict__ AGGcat)
{
  const size_t i4 = (size_t)blockIdx.x*256 + threadIdx.x;  // 524288 float4s
  float4 sv = make_float4(0.f,0.f,0.f,0.f);
  for (int kp=0; kp<kparts; kp++) {
    float4 v = ((const float4*)(parts + (size_t)kp*kpC))[i4];
    sv.x+=v.x; sv.y+=v.y; sv.z+=v.z; sv.w+=v.w;
  }
  const size_t flat = i4*4;
  const size_t row = flat >> 8;
  const int d = (int)(flat & 255);
  float a[4] = {sv.x, sv.y, sv.z, sv.w};
  ushort4 hi, lo;
  { ushort h=f2bf(a[0]); hi.x=h; lo.x=f2bf(a[0]-bf2f(h)); }
  { ushort h=f2bf(a[1]); hi.y=h; lo.y=f2bf(a[1]-bf2f(h)); }
  { ushort h=f2bf(a[2]); hi.z=h; lo.z=f2bf(a[2]-bf2f(h)); }
  { ushort h=f2bf(a[3]); hi.w=h; lo.w=f2bf(a[3]-bf2f(h)); }
  ushort* dst = AGGcat + row*512 + d;
  *(ushort4*)dst = hi; *(ushort4*)(dst+256) = lo;
}

// ===================== softmax =====================
// per (b,d): max & 1/sum over e of ESt [b][256][2048] f32
__global__ __launch_bounds__(256)
void stats_kernel(const float* __restrict__ ESt, float2* __restrict__ stats)
{
  const int b = blockIdx.x >> 8, d = blockIdx.x & 255;
  const float* base = ESt + ((size_t)b*256 + d)*2048;
  const int t = threadIdx.x;
  const float4* p = (const float4*)base + t*2;
  float4 x = p[0], y = p[1];
  float v[8] = {x.x,x.y,x.z,x.w,y.x,y.y,y.z,y.w};
  float mx = v[0];
  #pragma unroll
  for (int j=1;j<8;j++) mx = fmaxf(mx, v[j]);
  #pragma unroll
  for (int off=32; off>=1; off>>=1) mx = fmaxf(mx, __shfl_down(mx, off));
  __shared__ float sm[8];
  const int lane = t & 63, w = t >> 6;
  if (lane==0) sm[w] = mx;
  __syncthreads();
  if (t==0) { sm[4] = fmaxf(fmaxf(sm[0],sm[1]),fmaxf(sm[2],sm[3])); }
  __syncthreads();
  mx = sm[4];
  float s = 0.f;
  #pragma unroll
  for (int j=0;j<8;j++) s += __expf(v[j]-mx);
  #pragma unroll
  for (int off=32; off>=1; off>>=1) s += __shfl_down(s, off);
  if (lane==0) sm[w] = s;
  __syncthreads();
  if (t==0) { float ss = sm[0]+sm[1]+sm[2]+sm[3]; stats[blockIdx.x] = make_float2(mx, 1.f/ss); }
}

// P[b][e][d] = exp(ES-mx)*inv * (Ah+Al)
__global__ __launch_bounds__(256)
void pmul_kernel(const float* __restrict__ ES, const ushort* __restrict__ AGGcat,
                 const float2* __restrict__ stats, ushort* __restrict__ P)
{
  const int b = blockIdx.x >> 6, e0 = (blockIdx.x & 63) * 32;
  const int t = threadIdx.x, tx = t & 63, ty = t >> 6;
  const int d4 = tx*4;
  const float2 st0 = stats[b*256+d4+0], st1 = stats[b*256+d4+1];
  const float2 st2 = stats[b*256+d4+2], st3 = stats[b*256+d4+3];
  for (int e = e0+ty; e < e0+32; e += 4) {
    const size_t ro = (size_t)b*2048 + e;
    float4 es = *(const float4*)(ES + ro*256 + d4);
    ushort4 ah = *(const ushort4*)(AGGcat + ro*512 + d4);
    ushort4 al = *(const ushort4*)(AGGcat + ro*512 + 256 + d4);
    ushort4 o;
    o.x = f2bf(__expf(es.x-st0.x)*st0.y*(bf2f(ah.x)+bf2f(al.x)));
    o.y = f2bf(__expf(es.y-st1.x)*st1.y*(bf2f(ah.y)+bf2f(al.y)));
    o.z = f2bf(__expf(es.z-st2.x)*st2.y*(bf2f(ah.z)+bf2f(al.z)));
    o.w = f2bf(__expf(es.w-st3.x)*st3.y*(bf2f(ah.w)+bf2f(al.w)));
    *(ushort4*)(P + ro*256 + d4) = o;
  }
}

__global__ __launch_bounds__(256)
void inc_copy_kernel(const f32x4* __restrict__ src, f32x4* __restrict__ dst, size_t n4)
{
  size_t i = (size_t)blockIdx.x*256 + threadIdx.x;
  const size_t stride = (size_t)gridDim.x*256;
  for (; i < n4; i += stride)
    __builtin_nontemporal_store(__builtin_nontemporal_load(src + i), dst + i);
}

// ===================== host =====================
extern "C" void kernel_launch(void* const* d_in, const int* in_sizes, int n_in,
                              void* d_out, int out_size, void* d_ws, size_t ws_size,
                              hipStream_t stream) {
  const float* feat    = (const float*)d_in[0];
  const float* inc     = (const float*)d_in[1];
  const float* vcWatt  = (const float*)d_in[2];
  const float* vcWproj = (const float*)d_in[3];
  // d_in[4] vc_alpha: unused (edge_feats == ef_base every layer); d_in[5] ec_W_att: dead code
  const float* ecWproj = (const float*)d_in[6];
  const float* ecAlpha = (const float*)d_in[7];
  const int*   nLayers = (const int*)d_in[8];

  const int Bb=4, Mm=4096, E=2048, D=256;
  const size_t nodeN = (size_t)Bb*Mm*D, edgeN = (size_t)Bb*E*D, incN = (size_t)Bb*Mm*E;

  const int kparts = 8;
  const size_t fTB    = (size_t)Bb*256*8192*2;   // 16.78 MB
  const size_t partsB = (size_t)kparts*Bb*E*D*4; // 67.1 MB
  const size_t AGGcatB= (size_t)Bb*E*512*2;      // 8.39 MB
  const size_t ESB    = (size_t)Bb*E*D*4;        // 8.39 MB
  const size_t EStB   = ESB;                     // 8.39 MB
  const size_t PB     = edgeN*2;                 // 4.19 MB
  const size_t edgeTB = edgeN*2;                 // 4.19 MB
  const size_t WtB    = nodeN*2;                 // 8.39 MB
  const size_t WsB    = (size_t)3*256*512*2;
  const size_t statB  = (size_t)Bb*256*sizeof(float2);
  const size_t incTB  = incN*2, incbfB = incN*2; // 67.1 MB each
  const size_t needB  = fTB+partsB+AGGcatB+ESB+EStB+PB+edgeTB+WtB+WsB+statB;
  const bool planA = ws_size >= needB + incTB + incbfB;

  char* ws = (char*)d_ws;
  ushort* fT    = (ushort*)ws;  ws += fTB;
  float*  parts = (float*)ws;   ws += partsB;
  ushort* AGGcat= (ushort*)ws;  ws += AGGcatB;
  float*  ES    = (float*)ws;   ws += ESB;
  float*  ESt   = (float*)ws;   ws += EStB;
  ushort* P     = (ushort*)ws;  ws += PB;
  ushort* edgeT = (ushort*)ws;  ws += edgeTB;
  ushort* Wt    = (ushort*)ws;  ws += WtB;
  ushort* Ws0   = (ushort*)ws;            // vc_W_att
  ushort* Ws1   = Ws0 + 256*512;          // vc_W_proj
  ushort* Ws2   = Ws1 + 256*512;          // ec_W_proj
  ws += WsB;
  float2* stats = (float2*)ws;  ws += statB;

  float* outNode = (float*)d_out;
  float* outEdge = outNode + nodeN;
  float* outInc  = outEdge + edgeN;
  ushort* incT, *incbf;
  if (planA) { incT = (ushort*)ws; incbf = incT + incN; }
  else       { incT = (ushort*)outInc; incbf = incT + incN; }  // scratch in outInc, fixed by copy

  const long long kpC = (long long)Bb*E*D;  // part stride (floats)
  dim3 blk(256);

  // 0. weight splits + input transposes
  cvt_w_kernel<<<dim3(64), blk, 0, stream>>>((const float4*)vcWatt,  Ws0);
  cvt_w_kernel<<<dim3(64), blk, 0, stream>>>((const float4*)vcWproj, Ws1);
  cvt_w_kernel<<<dim3(64), blk, 0, stream>>>((const float4*)ecWproj, Ws2);
  trans_feat_kernel<<<dim3(64,4,4), blk, 0, stream>>>(feat, fT);
  trans_inc_kernel<<<dim3(64,32,4), blk, 0, stream>>>(inc, outInc, planA ? 1 : 0, incbf, incT);

  // 1. AGG parts = incT @ fT^T   (K=8192: fh then fl, inc wraps; split-K)
  gemm_kernel<1,0,0,4><<<dim3(2,16,4*kparts), blk, 0, stream>>>(
      incT, 4096, (long long)E*4096, fT, 8192, (long long)256*8192,
      parts, nullptr, D, (long long)E*D, 0, 0, kpC, 8192/kparts, kparts,
      nullptr, nullptr, nullptr);

  // 2. sum parts -> AGGcat [e][512] = [Ah|Al]
  aggsum_kernel<<<dim3(2048), blk, 0, stream>>>(parts, kpC, kparts, AGGcat);

  // 3. ES = AGG @ vcWatt^T  (4-term hi/lo, K=1024) -> f32 [e][256] + transposed [256][2048]
  gemm_kernel<5,3,6,2><<<dim3(4,32,4), blk, 0, stream>>>(
      AGGcat, 512, (long long)E*512, Ws0, 512, 0,
      ES, ESt, D, (long long)E*D, E, (long long)D*E, 0, 1024, 1,
      nullptr, nullptr, nullptr);

  // 4. softmax stats + P
  stats_kernel<<<dim3(Bb*256), blk, 0, stream>>>(ESt, stats);
  pmul_kernel<<<dim3(Bb*64), blk, 0, stream>>>(ES, AGGcat, stats, P);

  // 5. edge_out = P @ vcWproj^T (K=512 hi/lo) -> f32 out + bf16 transposed edgeT
  gemm_kernel<4,3,7,2><<<dim3(4,32,4), blk, 0, stream>>>(
      P, 256, (long long)E*D, Ws1, 512, 0,
      outEdge, edgeT, D, (long long)E*D, E, (long long)D*E, 0, 512, 1,
      nullptr, nullptr, nullptr);

  // 6. Wt = inc @ edge_out  (K=2048) -> bf16
  gemm_kernel<0,0,1,2><<<dim3(4,64,4), blk, 0, stream>>>(
      incbf, 2048, (long long)Mm*E, edgeT, 2048, (long long)D*E,
      Wt, nullptr, D, (long long)Mm*D, 0, 0, 0, 2048, 1,
      nullptr, nullptr, nullptr);

  // 7. node_out = a^L*feat + (1-a^L)*(Wt @ ecWproj^T)  (K=512 dup/hi-lo)
  gemm_kernel<4,3,2,2><<<dim3(4,64,4), blk, 0, stream>>>(
      Wt, 256, (long long)Mm*D, Ws2, 512, 0,
      outNode, nullptr, D, (long long)Mm*D, 0, 0, 0, 512, 1,
      feat, ecAlpha, nLayers);

  // 8. plan B: restore inc passthrough (overwrites incT/incbf scratch)
  if (!planA)
    inc_copy_kernel<<<dim3(2048), blk, 0, stream>>>((const f32x4*)inc, (f32x4*)outInc, incN/4);
}

// Round 7
// 527.690 us; speedup vs baseline: 1.2412x; 1.2412x over previous
//
#include <hip/hip_runtime.h>
#include <hip/hip_bf16.h>
#include <math.h>

typedef __attribute__((ext_vector_type(8))) short s8v;     // 8 bf16
typedef __attribute__((ext_vector_type(4))) float f32x4;   // MFMA C/D

__device__ __forceinline__ ushort f2bf(float x){ __hip_bfloat16 h = __float2bfloat16(x); return *(ushort*)&h; }
__device__ __forceinline__ float  bf2f(ushort u){ return __bfloat162float(*(__hip_bfloat16*)&u); }

// async global->LDS, 16B per lane; LDS dest = wave-uniform base + lane*16
__device__ __forceinline__ void gload16(const void* g, void* l) {
  __builtin_amdgcn_global_load_lds(
      (const __attribute__((address_space(1))) void*)g,
      (__attribute__((address_space(3))) void*)l, 16, 0, 0);
}

// K-index maps (applied at 8-element granularity; all preserve 8-contiguity)
// 0: identity   1: k&4095 (wrap: K=8192 over 4096 rows)
// 3: [Wh Wl Wh Wl] on [256][512]   4: [X X] (dup 256-col)   5: [Ah Ah Al Al] on [*][512]
template<int MAP> __device__ __forceinline__ int kmap(int k){
  if constexpr (MAP==0) return k;
  else if constexpr (MAP==1) return k & 4095;
  else if constexpr (MAP==3) return (((k>>8)&1)<<8) | (k&255);
  else if constexpr (MAP==4) return k & 255;
  else return (((k>>9)&1)<<8) | (k&255);
}

// ===================== GEMM (bf16 operands, global_load_lds staging) =====================
// A[M][K], B[N][K] (K contiguous). FR=4: 128x128 block. FR=2: 64x64 block.
// Grid: blockIdx.x = N-tiles (co-dispatched blocks share A-tile), blockIdx.y = M-tiles.
// EPI: 0 = f32 C (+kp part offset); 1 = bf16 C; 2 = blend f32 C = aL*blend+(1-aL)*v;
//      6 = f32 C + f32 transposed C2; 7 = f32 C + bf16 transposed C2
template<int AMAP, int BMAP, int EPI, int FR>
__global__ __launch_bounds__(256)
void gemm_kernel(const ushort* __restrict__ A, int lda, long long sA,
                 const ushort* __restrict__ B, int ldb, long long sB,
                 void* __restrict__ Cp, void* __restrict__ Cp2,
                 int ldc, long long sC, int ldc2, long long sC2,
                 long long kpC, int Kloc, int kparts,
                 const float* __restrict__ blend,
                 const float* __restrict__ alpha_p, const int* __restrict__ L_p)
{
  constexpr int BMt = 32*FR;
  __shared__ ushort As[BMt][32];   // linear, global_load_lds-compatible
  __shared__ ushort Bs[BMt][32];

  const int z  = blockIdx.z;
  const int b  = z / kparts;
  const int kp = z - b*kparts;
  const int kbase = kp * Kloc;
  A += (size_t)b * sA;
  B += (size_t)b * sB;
  const int m0 = blockIdx.y * BMt;
  const int n0 = blockIdx.x * BMt;
  const int t = threadIdx.x, lane = t & 63, wid = t >> 6;
  const int wr = (wid>>1)*(16*FR), wc = (wid&1)*(16*FR);
  const int lrow = lane & 15, koff = (lane>>4)<<3;
  const int rsub = lane >> 2;          // staging row within 16-row chunk
  const int kc   = (lane & 3) * 8;     // staging k-offset (8 bf16 = 16B)

  f32x4 acc[FR][FR];
  #pragma unroll
  for (int i=0;i<FR;i++)
    #pragma unroll
    for (int j=0;j<FR;j++) acc[i][j] = (f32x4)(0.f);

  for (int k0 = 0; k0 < Kloc; k0 += 32) {
    #pragma unroll
    for (int c = wid; c < 2*FR; c += 4) {
      const int row = c*16 + rsub;
      gload16(A + (size_t)(m0+row)*lda + kmap<AMAP>(kbase+k0+kc), (char*)&As[0][0] + c*1024);
      gload16(B + (size_t)(n0+row)*ldb + kmap<BMAP>(kbase+k0+kc), (char*)&Bs[0][0] + c*1024);
    }
    __syncthreads();
    s8v af[FR], bfv[FR];
    #pragma unroll
    for (int mi=0; mi<FR; mi++) af[mi]  = *(const s8v*)&As[wr+mi*16+lrow][koff];
    #pragma unroll
    for (int ni=0; ni<FR; ni++) bfv[ni] = *(const s8v*)&Bs[wc+ni*16+lrow][koff];
    #pragma unroll
    for (int mi=0; mi<FR; mi++)
      #pragma unroll
      for (int ni=0; ni<FR; ni++)
        acc[mi][ni] = __builtin_amdgcn_mfma_f32_16x16x32_bf16(af[mi], bfv[ni], acc[mi][ni], 0,0,0);
    __syncthreads();
  }

  float aL = 0.f;
  if constexpr (EPI==2) { aL = powf(*alpha_p, (float)(*L_p)); }
  const int cr = (lane>>4)<<2, cc = lane & 15;
  #pragma unroll
  for (int mi=0; mi<FR; mi++)
    #pragma unroll
    for (int ni=0; ni<FR; ni++) {
      const int row0 = m0 + wr + mi*16 + cr;
      const int col  = n0 + wc + ni*16 + cc;
      if constexpr (EPI==0) {
        float* C = (float*)Cp + kp*kpC + (size_t)b*sC;
        #pragma unroll
        for (int r=0;r<4;r++) C[(size_t)(row0+r)*ldc + col] = acc[mi][ni][r];
      } else if constexpr (EPI==1) {
        ushort* C = (ushort*)Cp + (size_t)b*sC;
        #pragma unroll
        for (int r=0;r<4;r++) C[(size_t)(row0+r)*ldc + col] = f2bf(acc[mi][ni][r]);
      } else if constexpr (EPI==2) {
        float* C = (float*)Cp + (size_t)b*sC;
        const float* bl = blend + (size_t)b*sC;
        #pragma unroll
        for (int r=0;r<4;r++) {
          const size_t idx = (size_t)(row0+r)*ldc + col;
          C[idx] = aL*bl[idx] + (1.f-aL)*acc[mi][ni][r];
        }
      } else if constexpr (EPI==6) {
        float* C = (float*)Cp + (size_t)b*sC;
        #pragma unroll
        for (int r=0;r<4;r++) C[(size_t)(row0+r)*ldc + col] = acc[mi][ni][r];
        float* C2 = (float*)Cp2 + (size_t)b*sC2 + (size_t)col*ldc2 + row0;
        *(f32x4*)C2 = acc[mi][ni];
      } else {  // EPI==7
        float* C = (float*)Cp + (size_t)b*sC;
        #pragma unroll
        for (int r=0;r<4;r++) C[(size_t)(row0+r)*ldc + col] = acc[mi][ni][r];
        ushort4 o;
        o.x = f2bf(acc[mi][ni][0]); o.y = f2bf(acc[mi][ni][1]);
        o.z = f2bf(acc[mi][ni][2]); o.w = f2bf(acc[mi][ni][3]);
        *(ushort4*)((ushort*)Cp2 + (size_t)b*sC2 + (size_t)col*ldc2 + row0) = o;
      }
    }
}

// ===================== Wt GEMM: A = f32 inc (reg-staged cvt), B = bf16 edgeT =====================
// C[m][d] = sum_e inc[m][e] * edgeT[d][e]; 64x64 tile; bf16 C out.
__global__ __launch_bounds__(256)
void gemm_wt_kernel(const float* __restrict__ A, int lda, long long sA,
                    const ushort* __restrict__ B, int ldb, long long sB,
                    ushort* __restrict__ Cp, int ldc, long long sC, int K)
{
  __shared__ ushort As[64][32];
  __shared__ ushort Bs[64][32];
  const int b = blockIdx.z;
  A += (size_t)b * sA;
  B += (size_t)b * sB;
  const int m0 = blockIdx.y * 64;
  const int n0 = blockIdx.x * 64;
  const int t = threadIdx.x, lane = t & 63, wid = t >> 6;
  const int wr = (wid>>1)*32, wc = (wid&1)*32;
  const int lrow = lane & 15, koff = (lane>>4)<<3;
  const int arow = t >> 2, ac8 = (t & 3) * 8;   // A staging: 8 f32 per thread
  const int rsub = lane >> 2, kc = (lane & 3) * 8;

  f32x4 acc[2][2];
  #pragma unroll
  for (int i=0;i<2;i++)
    #pragma unroll
    for (int j=0;j<2;j++) acc[i][j] = (f32x4)(0.f);

  for (int k0 = 0; k0 < K; k0 += 32) {
    // A: f32 -> bf16 reg-staged, contiguous ds_write (no conflicts)
    {
      const float* src = A + (size_t)(m0+arow)*lda + k0 + ac8;
      f32x4 v0 = *(const f32x4*)src;
      f32x4 v1 = *(const f32x4*)(src+4);
      s8v o;
      o[0]=(short)f2bf(v0[0]); o[1]=(short)f2bf(v0[1]); o[2]=(short)f2bf(v0[2]); o[3]=(short)f2bf(v0[3]);
      o[4]=(short)f2bf(v1[0]); o[5]=(short)f2bf(v1[1]); o[6]=(short)f2bf(v1[2]); o[7]=(short)f2bf(v1[3]);
      *(s8v*)&As[arow][ac8] = o;
    }
    // B: async direct-to-LDS
    if (wid < 4) {
      const int row = wid*16 + rsub;
      gload16(B + (size_t)(n0+row)*ldb + k0 + kc, (char*)&Bs[0][0] + wid*1024);
    }
    __syncthreads();
    s8v af[2], bfv[2];
    #pragma unroll
    for (int mi=0; mi<2; mi++) af[mi]  = *(const s8v*)&As[wr+mi*16+lrow][koff];
    #pragma unroll
    for (int ni=0; ni<2; ni++) bfv[ni] = *(const s8v*)&Bs[wc+ni*16+lrow][koff];
    #pragma unroll
    for (int mi=0; mi<2; mi++)
      #pragma unroll
      for (int ni=0; ni<2; ni++)
        acc[mi][ni] = __builtin_amdgcn_mfma_f32_16x16x32_bf16(af[mi], bfv[ni], acc[mi][ni], 0,0,0);
    __syncthreads();
  }

  const int cr = (lane>>4)<<2, cc = lane & 15;
  ushort* C = Cp + (size_t)b*sC;
  #pragma unroll
  for (int mi=0; mi<2; mi++)
    #pragma unroll
    for (int ni=0; ni<2; ni++) {
      const int row0 = m0 + wr + mi*16 + cr;
      const int col  = n0 + wc + ni*16 + cc;
      #pragma unroll
      for (int r=0;r<4;r++) C[(size_t)(row0+r)*ldc + col] = f2bf(acc[mi][ni][r]);
    }
}

// ===================== transposes =====================
// inc f32 [b][4096][2048] -> incT bf16 [b][2048][4096] (+ optional f32 passthrough to outInc)
__global__ __launch_bounds__(256)
void trans_inc_kernel(const float* __restrict__ src, float* __restrict__ outF32, int writeF32,
                      ushort* __restrict__ incT)
{
  __shared__ ushort T[64][65];
  const int b = blockIdx.z, m0 = blockIdx.x*64, e0 = blockIdx.y*64;
  const int t = threadIdx.x, rl = t>>2, cl = (t&3)*16;
  const size_t roff = (size_t)b*4096*2048 + (size_t)(m0+rl)*2048 + e0 + cl;
  const float* s = src + roff;
  ushort tmp[16] __attribute__((aligned(16)));
  float4 vv[4];
  #pragma unroll
  for (int i=0;i<4;i++) {
    vv[i] = ((const float4*)s)[i];
    tmp[4*i+0]=f2bf(vv[i].x); tmp[4*i+1]=f2bf(vv[i].y);
    tmp[4*i+2]=f2bf(vv[i].z); tmp[4*i+3]=f2bf(vv[i].w);
  }
  if (writeF32) {
    float4* o = (float4*)(outF32 + roff);
    #pragma unroll
    for (int i=0;i<4;i++) o[i] = vv[i];
  }
  #pragma unroll
  for (int j=0;j<16;j++) T[rl][cl+j] = tmp[j];
  __syncthreads();
  const int er = t>>2, mc = (t&3)*16;
  ushort o[16] __attribute__((aligned(16)));
  #pragma unroll
  for (int j=0;j<16;j++) o[j] = T[mc+j][er];
  ushort* d2 = incT + (size_t)b*2048*4096 + (size_t)(e0+er)*4096 + m0 + mc;
  *(s8v*)d2 = *(s8v*)&o[0]; *(s8v*)(d2+8) = *(s8v*)&o[8];
}

// feat f32 [b][4096][256] -> fT bf16 [b][256][8192]: hi at col m, lo at col 4096+m
__global__ __launch_bounds__(256)
void trans_feat_kernel(const float* __restrict__ feat, ushort* __restrict__ fT)
{
  __shared__ ushort Th[64][65], Tl[64][65];
  const int b = blockIdx.z, m0 = blockIdx.x*64, d0 = blockIdx.y*64;
  const int t = threadIdx.x, rl = t>>2, cl = (t&3)*16;
  const float* s = feat + (size_t)b*4096*256 + (size_t)(m0+rl)*256 + d0 + cl;
  #pragma unroll
  for (int i=0;i<4;i++) {
    float4 v = ((const float4*)s)[i];
    float a[4] = {v.x,v.y,v.z,v.w};
    #pragma unroll
    for (int j=0;j<4;j++) {
      ushort h = f2bf(a[j]); Th[rl][cl+4*i+j] = h; Tl[rl][cl+4*i+j] = f2bf(a[j] - bf2f(h));
    }
  }
  __syncthreads();
  const int dr = t>>2, mc = (t&3)*16;
  ushort oh[16] __attribute__((aligned(16)));
  ushort ol[16] __attribute__((aligned(16)));
  #pragma unroll
  for (int j=0;j<16;j++) { oh[j] = Th[mc+j][dr]; ol[j] = Tl[mc+j][dr]; }
  ushort* d2 = fT + (size_t)b*256*8192 + (size_t)(d0+dr)*8192 + m0 + mc;
  *(s8v*)d2 = *(s8v*)&oh[0]; *(s8v*)(d2+8) = *(s8v*)&oh[8];
  *(s8v*)(d2+4096) = *(s8v*)&ol[0]; *(s8v*)(d2+4104) = *(s8v*)&ol[8];
}

// W f32 [256][256] -> Ws [256][512] = [Wh | Wl]
__global__ __launch_bounds__(256)
void cvt_w_kernel(const float4* __restrict__ W, ushort* __restrict__ Ws)
{
  size_t i  = (size_t)blockIdx.x * 256 + threadIdx.x;
  size_t e0 = i * 4;
  int c = (int)(e0 & 255), r = (int)(e0 >> 8);
  float4 v = W[i];
  float a[4] = {v.x,v.y,v.z,v.w};
  ushort* hi = Ws + (size_t)r*512 + c;
  #pragma unroll
  for (int j=0;j<4;j++) { ushort h = f2bf(a[j]); hi[j] = h; hi[256+j] = f2bf(a[j]-bf2f(h)); }
}

// sum split-K AGG parts -> AGGcat bf16 [b*2048][512] = [Ah | Al]
__global__ __launch_bounds__(256)
void aggsum_kernel(const float* __restrict__ parts, long long kpC, int kparts,
                   ushort* __restrict__ AGGcat)
{
  const size_t i4 = (size_t)blockIdx.x*256 + threadIdx.x;  // 524288 float4s
  float4 sv = make_float4(0.f,0.f,0.f,0.f);
  for (int kp=0; kp<kparts; kp++) {
    float4 v = ((const float4*)(parts + (size_t)kp*kpC))[i4];
    sv.x+=v.x; sv.y+=v.y; sv.z+=v.z; sv.w+=v.w;
  }
  const size_t flat = i4*4;
  const size_t row = flat >> 8;
  const int d = (int)(flat & 255);
  float a[4] = {sv.x, sv.y, sv.z, sv.w};
  ushort4 hi, lo;
  { ushort h=f2bf(a[0]); hi.x=h; lo.x=f2bf(a[0]-bf2f(h)); }
  { ushort h=f2bf(a[1]); hi.y=h; lo.y=f2bf(a[1]-bf2f(h)); }
  { ushort h=f2bf(a[2]); hi.z=h; lo.z=f2bf(a[2]-bf2f(h)); }
  { ushort h=f2bf(a[3]); hi.w=h; lo.w=f2bf(a[3]-bf2f(h)); }
  ushort* dst = AGGcat + row*512 + d;
  *(ushort4*)dst = hi; *(ushort4*)(dst+256) = lo;
}

// ===================== softmax =====================
// per (b,d): max & 1/sum over e of ESt [b][256][2048] f32
__global__ __launch_bounds__(256)
void stats_kernel(const float* __restrict__ ESt, float2* __restrict__ stats)
{
  const int b = blockIdx.x >> 8, d = blockIdx.x & 255;
  const float* base = ESt + ((size_t)b*256 + d)*2048;
  const int t = threadIdx.x;
  const float4* p = (const float4*)base + t*2;
  float4 x = p[0], y = p[1];
  float v[8] = {x.x,x.y,x.z,x.w,y.x,y.y,y.z,y.w};
  float mx = v[0];
  #pragma unroll
  for (int j=1;j<8;j++) mx = fmaxf(mx, v[j]);
  #pragma unroll
  for (int off=32; off>=1; off>>=1) mx = fmaxf(mx, __shfl_down(mx, off));
  __shared__ float sm[8];
  const int lane = t & 63, w = t >> 6;
  if (lane==0) sm[w] = mx;
  __syncthreads();
  if (t==0) { sm[4] = fmaxf(fmaxf(sm[0],sm[1]),fmaxf(sm[2],sm[3])); }
  __syncthreads();
  mx = sm[4];
  float s = 0.f;
  #pragma unroll
  for (int j=0;j<8;j++) s += __expf(v[j]-mx);
  #pragma unroll
  for (int off=32; off>=1; off>>=1) s += __shfl_down(s, off);
  if (lane==0) sm[w] = s;
  __syncthreads();
  if (t==0) { float ss = sm[0]+sm[1]+sm[2]+sm[3]; stats[blockIdx.x] = make_float2(mx, 1.f/ss); }
}

// P[b][e][d] = exp(ES-mx)*inv * (Ah+Al)
__global__ __launch_bounds__(256)
void pmul_kernel(const float* __restrict__ ES, const ushort* __restrict__ AGGcat,
                 const float2* __restrict__ stats, ushort* __restrict__ P)
{
  const int b = blockIdx.x >> 6, e0 = (blockIdx.x & 63) * 32;
  const int t = threadIdx.x, tx = t & 63, ty = t >> 6;
  const int d4 = tx*4;
  const float2 st0 = stats[b*256+d4+0], st1 = stats[b*256+d4+1];
  const float2 st2 = stats[b*256+d4+2], st3 = stats[b*256+d4+3];
  for (int e = e0+ty; e < e0+32; e += 4) {
    const size_t ro = (size_t)b*2048 + e;
    float4 es = *(const float4*)(ES + ro*256 + d4);
    ushort4 ah = *(const ushort4*)(AGGcat + ro*512 + d4);
    ushort4 al = *(const ushort4*)(AGGcat + ro*512 + 256 + d4);
    ushort4 o;
    o.x = f2bf(__expf(es.x-st0.x)*st0.y*(bf2f(ah.x)+bf2f(al.x)));
    o.y = f2bf(__expf(es.y-st1.x)*st1.y*(bf2f(ah.y)+bf2f(al.y)));
    o.z = f2bf(__expf(es.z-st2.x)*st2.y*(bf2f(ah.z)+bf2f(al.z)));
    o.w = f2bf(__expf(es.w-st3.x)*st3.y*(bf2f(ah.w)+bf2f(al.w)));
    *(ushort4*)(P + ro*256 + d4) = o;
  }
}

__global__ __launch_bounds__(256)
void inc_copy_kernel(const float4* __restrict__ src, float4* __restrict__ dst, size_t n4)
{
  size_t i = (size_t)blockIdx.x*256 + threadIdx.x;
  const size_t stride = (size_t)gridDim.x*256;
  for (; i < n4; i += stride) dst[i] = src[i];
}

// ===================== host =====================
extern "C" void kernel_launch(void* const* d_in, const int* in_sizes, int n_in,
                              void* d_out, int out_size, void* d_ws, size_t ws_size,
                              hipStream_t stream) {
  const float* feat    = (const float*)d_in[0];
  const float* inc     = (const float*)d_in[1];
  const float* vcWatt  = (const float*)d_in[2];
  const float* vcWproj = (const float*)d_in[3];
  // d_in[4] vc_alpha: unused (edge_feats == ef_base every layer); d_in[5] ec_W_att: dead code
  const float* ecWproj = (const float*)d_in[6];
  const float* ecAlpha = (const float*)d_in[7];
  const int*   nLayers = (const int*)d_in[8];

  const int Bb=4, Mm=4096, E=2048, D=256;
  const size_t nodeN = (size_t)Bb*Mm*D, edgeN = (size_t)Bb*E*D, incN = (size_t)Bb*Mm*E;

  const int kparts = 8;
  const size_t fTB    = (size_t)Bb*256*8192*2;   // 16.78 MB
  const size_t partsB = (size_t)kparts*Bb*E*D*4; // 67.1 MB
  const size_t AGGcatB= (size_t)Bb*E*512*2;      // 8.39 MB
  const size_t ESB    = (size_t)Bb*E*D*4;        // 8.39 MB
  const size_t EStB   = ESB;                     // 8.39 MB
  const size_t PB     = edgeN*2;                 // 4.19 MB
  const size_t edgeTB = edgeN*2;                 // 4.19 MB
  const size_t WtB    = nodeN*2;                 // 8.39 MB
  const size_t WsB    = (size_t)3*256*512*2;
  const size_t statB  = (size_t)Bb*256*sizeof(float2);
  const size_t incTB  = incN*2;                  // 67.1 MB
  const size_t needB  = fTB+partsB+AGGcatB+ESB+EStB+PB+edgeTB+WtB+WsB+statB;
  const bool planA = ws_size >= needB + incTB;

  char* ws = (char*)d_ws;
  ushort* fT    = (ushort*)ws;  ws += fTB;
  float*  parts = (float*)ws;   ws += partsB;
  ushort* AGGcat= (ushort*)ws;  ws += AGGcatB;
  float*  ES    = (float*)ws;   ws += ESB;
  float*  ESt   = (float*)ws;   ws += EStB;
  ushort* P     = (ushort*)ws;  ws += PB;
  ushort* edgeT = (ushort*)ws;  ws += edgeTB;
  ushort* Wt    = (ushort*)ws;  ws += WtB;
  ushort* Ws0   = (ushort*)ws;            // vc_W_att
  ushort* Ws1   = Ws0 + 256*512;          // vc_W_proj
  ushort* Ws2   = Ws1 + 256*512;          // ec_W_proj
  ws += WsB;
  float2* stats = (float2*)ws;  ws += statB;

  float* outNode = (float*)d_out;
  float* outEdge = outNode + nodeN;
  float* outInc  = outEdge + edgeN;
  ushort* incT = planA ? (ushort*)ws : (ushort*)outInc;  // plan B: scratch in outInc, fixed by copy

  const long long kpC = (long long)Bb*E*D;  // part stride (floats)
  dim3 blk(256);

  // 0. weight splits + input transposes
  cvt_w_kernel<<<dim3(64), blk, 0, stream>>>((const float4*)vcWatt,  Ws0);
  cvt_w_kernel<<<dim3(64), blk, 0, stream>>>((const float4*)vcWproj, Ws1);
  cvt_w_kernel<<<dim3(64), blk, 0, stream>>>((const float4*)ecWproj, Ws2);
  trans_feat_kernel<<<dim3(64,4,4), blk, 0, stream>>>(feat, fT);
  trans_inc_kernel<<<dim3(64,32,4), blk, 0, stream>>>(inc, outInc, planA ? 1 : 0, incT);

  // 1. AGG parts = incT @ fT^T   (K=8192: fh then fl, inc wraps; split-K)
  gemm_kernel<1,0,0,4><<<dim3(2,16,4*kparts), blk, 0, stream>>>(
      incT, 4096, (long long)E*4096, fT, 8192, (long long)256*8192,
      parts, nullptr, D, (long long)E*D, 0, 0, kpC, 8192/kparts, kparts,
      nullptr, nullptr, nullptr);

  // 2. sum parts -> AGGcat [e][512] = [Ah|Al]
  aggsum_kernel<<<dim3(2048), blk, 0, stream>>>(parts, kpC, kparts, AGGcat);

  // 3. ES = AGG @ vcWatt^T  (4-term hi/lo, K=1024) -> f32 [e][256] + transposed [256][2048]
  gemm_kernel<5,3,6,2><<<dim3(4,32,4), blk, 0, stream>>>(
      AGGcat, 512, (long long)E*512, Ws0, 512, 0,
      ES, ESt, D, (long long)E*D, E, (long long)D*E, 0, 1024, 1,
      nullptr, nullptr, nullptr);

  // 4. softmax stats + P
  stats_kernel<<<dim3(Bb*256), blk, 0, stream>>>(ESt, stats);
  pmul_kernel<<<dim3(Bb*64), blk, 0, stream>>>(ES, AGGcat, stats, P);

  // 5. edge_out = P @ vcWproj^T (K=512 hi/lo) -> f32 out + bf16 transposed edgeT
  gemm_kernel<4,3,7,2><<<dim3(4,32,4), blk, 0, stream>>>(
      P, 256, (long long)E*D, Ws1, 512, 0,
      outEdge, edgeT, D, (long long)E*D, E, (long long)D*E, 0, 512, 1,
      nullptr, nullptr, nullptr);

  // 6. Wt = inc(f32, reg-staged) @ edgeT  (K=2048) -> bf16
  gemm_wt_kernel<<<dim3(4,64,4), blk, 0, stream>>>(
      inc, 2048, (long long)Mm*E, edgeT, 2048, (long long)D*E,
      Wt, D, (long long)Mm*D, 2048);

  // 7. node_out = a^L*feat + (1-a^L)*(Wt @ ecWproj^T)  (K=512 dup/hi-lo)
  gemm_kernel<4,3,2,2><<<dim3(4,64,4), blk, 0, stream>>>(
      Wt, 256, (long long)Mm*D, Ws2, 512, 0,
      outNode, nullptr, D, (long long)Mm*D, 0, 0, 0, 512, 1,
      feat, ecAlpha, nLayers);

  // 8. plan B: restore inc passthrough (overwrites incT scratch)
  if (!planA)
    inc_copy_kernel<<<dim3(2048), blk, 0, stream>>>((const float4*)inc, (float4*)outInc, incN/4);
}

// Round 8
// 512.082 us; speedup vs baseline: 1.2790x; 1.0305x over previous
//
#include <hip/hip_runtime.h>
#include <hip/hip_bf16.h>
#include <math.h>

typedef __attribute__((ext_vector_type(8))) short s8v;     // 8 bf16
typedef __attribute__((ext_vector_type(4))) float f32x4;   // MFMA C/D

__device__ __forceinline__ ushort f2bf(float x){ __hip_bfloat16 h = __float2bfloat16(x); return *(ushort*)&h; }
__device__ __forceinline__ float  bf2f(ushort u){ return __bfloat162float(*(__hip_bfloat16*)&u); }

// async global->LDS, 16B per lane; LDS dest = wave-uniform base + lane*16
__device__ __forceinline__ void gload16(const void* g, void* l) {
  __builtin_amdgcn_global_load_lds(
      (const __attribute__((address_space(1))) void*)g,
      (__attribute__((address_space(3))) void*)l, 16, 0, 0);
}

// K-index maps (applied at 8-element granularity; all preserve 8-contiguity)
// 0: identity   1: k&4095 (wrap: K=8192 over 4096 rows)
// 3: [Wh Wl Wh Wl] on [256][512]   4: [X X] (dup 256-col)   5: [Ah Ah Al Al] on [*][512]
template<int MAP> __device__ __forceinline__ int kmap(int k){
  if constexpr (MAP==0) return k;
  else if constexpr (MAP==1) return k & 4095;
  else if constexpr (MAP==3) return (((k>>8)&1)<<8) | (k&255);
  else if constexpr (MAP==4) return k & 255;
  else return (((k>>9)&1)<<8) | (k&255);
}

// ===================== GEMM (bf16 operands, global_load_lds staging) =====================
// A[M][K], B[N][K] (K contiguous). FR=4: 128x128 block. FR=2: 64x64 block.
// GORD=0: blockIdx.x = N-tiles, y = M-tiles.  GORD=1: blockIdx.x = M-tiles, y = N-tiles
// (use GORD=1 when A is the big streamed operand: each A-panel read by one block sequence,
//  avoids cross-XCD duplicate fetches of shared panels).
// EPI: 0 = f32 C (+kp part offset); 2 = blend f32 C = aL*blend+(1-aL)*v;
//      3 = f32 C + straight bf16 C2; 6 = f32 C + f32 transposed C2; 8 = bf16 transposed C2 only
template<int AMAP, int BMAP, int EPI, int FR, int GORD>
__global__ __launch_bounds__(256)
void gemm_kernel(const ushort* __restrict__ A, int lda, long long sA,
                 const ushort* __restrict__ B, int ldb, long long sB,
                 void* __restrict__ Cp, void* __restrict__ Cp2,
                 int ldc, long long sC, int ldc2, long long sC2,
                 long long kpC, int Kloc, int kparts,
                 const float* __restrict__ blend,
                 const float* __restrict__ alpha_p, const int* __restrict__ L_p)
{
  constexpr int BMt = 32*FR;
  __shared__ ushort As[BMt][32];   // linear, global_load_lds-compatible
  __shared__ ushort Bs[BMt][32];

  const int z  = blockIdx.z;
  const int b  = z / kparts;
  const int kp = z - b*kparts;
  const int kbase = kp * Kloc;
  A += (size_t)b * sA;
  B += (size_t)b * sB;
  const int m0 = (GORD ? blockIdx.x : blockIdx.y) * BMt;
  const int n0 = (GORD ? blockIdx.y : blockIdx.x) * BMt;
  const int t = threadIdx.x, lane = t & 63, wid = t >> 6;
  const int wr = (wid>>1)*(16*FR), wc = (wid&1)*(16*FR);
  const int lrow = lane & 15, koff = (lane>>4)<<3;
  const int rsub = lane >> 2;          // staging row within 16-row chunk
  const int kc   = (lane & 3) * 8;     // staging k-offset (8 bf16 = 16B)

  f32x4 acc[FR][FR];
  #pragma unroll
  for (int i=0;i<FR;i++)
    #pragma unroll
    for (int j=0;j<FR;j++) acc[i][j] = (f32x4)(0.f);

  for (int k0 = 0; k0 < Kloc; k0 += 32) {
    #pragma unroll
    for (int c = wid; c < 2*FR; c += 4) {
      const int row = c*16 + rsub;
      gload16(A + (size_t)(m0+row)*lda + kmap<AMAP>(kbase+k0+kc), (char*)&As[0][0] + c*1024);
      gload16(B + (size_t)(n0+row)*ldb + kmap<BMAP>(kbase+k0+kc), (char*)&Bs[0][0] + c*1024);
    }
    __syncthreads();
    s8v af[FR], bfv[FR];
    #pragma unroll
    for (int mi=0; mi<FR; mi++) af[mi]  = *(const s8v*)&As[wr+mi*16+lrow][koff];
    #pragma unroll
    for (int ni=0; ni<FR; ni++) bfv[ni] = *(const s8v*)&Bs[wc+ni*16+lrow][koff];
    #pragma unroll
    for (int mi=0; mi<FR; mi++)
      #pragma unroll
      for (int ni=0; ni<FR; ni++)
        acc[mi][ni] = __builtin_amdgcn_mfma_f32_16x16x32_bf16(af[mi], bfv[ni], acc[mi][ni], 0,0,0);
    __syncthreads();
  }

  float aL = 0.f;
  if constexpr (EPI==2) { aL = powf(*alpha_p, (float)(*L_p)); }
  const int cr = (lane>>4)<<2, cc = lane & 15;
  #pragma unroll
  for (int mi=0; mi<FR; mi++)
    #pragma unroll
    for (int ni=0; ni<FR; ni++) {
      const int row0 = m0 + wr + mi*16 + cr;
      const int col  = n0 + wc + ni*16 + cc;
      if constexpr (EPI==0) {
        float* C = (float*)Cp + kp*kpC + (size_t)b*sC;
        #pragma unroll
        for (int r=0;r<4;r++) C[(size_t)(row0+r)*ldc + col] = acc[mi][ni][r];
      } else if constexpr (EPI==2) {
        float* C = (float*)Cp + (size_t)b*sC;
        const float* bl = blend + (size_t)b*sC;
        #pragma unroll
        for (int r=0;r<4;r++) {
          const size_t idx = (size_t)(row0+r)*ldc + col;
          C[idx] = aL*bl[idx] + (1.f-aL)*acc[mi][ni][r];
        }
      } else if constexpr (EPI==3) {
        float* C = (float*)Cp + (size_t)b*sC;
        ushort* C2 = (ushort*)Cp2 + (size_t)b*sC;
        #pragma unroll
        for (int r=0;r<4;r++) {
          const size_t idx = (size_t)(row0+r)*ldc + col;
          C[idx] = acc[mi][ni][r];
          C2[idx] = f2bf(acc[mi][ni][r]);
        }
      } else if constexpr (EPI==6) {
        float* C = (float*)Cp + (size_t)b*sC;
        #pragma unroll
        for (int r=0;r<4;r++) C[(size_t)(row0+r)*ldc + col] = acc[mi][ni][r];
        float* C2 = (float*)Cp2 + (size_t)b*sC2 + (size_t)col*ldc2 + row0;
        *(f32x4*)C2 = acc[mi][ni];
      } else {  // EPI==8: bf16 transposed only
        ushort4 o;
        o.x = f2bf(acc[mi][ni][0]); o.y = f2bf(acc[mi][ni][1]);
        o.z = f2bf(acc[mi][ni][2]); o.w = f2bf(acc[mi][ni][3]);
        *(ushort4*)((ushort*)Cp2 + (size_t)b*sC2 + (size_t)col*ldc2 + row0) = o;
      }
    }
}

// ===================== transposes =====================
// inc f32 [b][4096][2048] -> outInc f32 (plan A) + incbf bf16 straight + incT bf16 [b][2048][4096]
__global__ __launch_bounds__(256)
void trans_inc_kernel(const float* __restrict__ src, float* __restrict__ outF32, int writeF32,
                      ushort* __restrict__ incbf, ushort* __restrict__ incT)
{
  __shared__ ushort T[64][65];
  const int b = blockIdx.z, m0 = blockIdx.x*64, e0 = blockIdx.y*64;
  const int t = threadIdx.x, rl = t>>2, cl = (t&3)*16;
  const size_t roff = (size_t)b*4096*2048 + (size_t)(m0+rl)*2048 + e0 + cl;
  const float* s = src + roff;
  ushort tmp[16] __attribute__((aligned(16)));
  float4 vv[4];
  #pragma unroll
  for (int i=0;i<4;i++) {
    vv[i] = ((const float4*)s)[i];
    tmp[4*i+0]=f2bf(vv[i].x); tmp[4*i+1]=f2bf(vv[i].y);
    tmp[4*i+2]=f2bf(vv[i].z); tmp[4*i+3]=f2bf(vv[i].w);
  }
  if (writeF32) {
    float4* o = (float4*)(outF32 + roff);
    #pragma unroll
    for (int i=0;i<4;i++) o[i] = vv[i];
  }
  ushort* d = incbf + roff;
  *(s8v*)d = *(s8v*)&tmp[0]; *(s8v*)(d+8) = *(s8v*)&tmp[8];
  #pragma unroll
  for (int j=0;j<16;j++) T[rl][cl+j] = tmp[j];
  __syncthreads();
  const int er = t>>2, mc = (t&3)*16;
  ushort o[16] __attribute__((aligned(16)));
  #pragma unroll
  for (int j=0;j<16;j++) o[j] = T[mc+j][er];
  ushort* d2 = incT + (size_t)b*2048*4096 + (size_t)(e0+er)*4096 + m0 + mc;
  *(s8v*)d2 = *(s8v*)&o[0]; *(s8v*)(d2+8) = *(s8v*)&o[8];
}

// feat f32 [b][4096][256] -> fT bf16 [b][256][8192]: hi at col m, lo at col 4096+m
__global__ __launch_bounds__(256)
void trans_feat_kernel(const float* __restrict__ feat, ushort* __restrict__ fT)
{
  __shared__ ushort Th[64][65], Tl[64][65];
  const int b = blockIdx.z, m0 = blockIdx.x*64, d0 = blockIdx.y*64;
  const int t = threadIdx.x, rl = t>>2, cl = (t&3)*16;
  const float* s = feat + (size_t)b*4096*256 + (size_t)(m0+rl)*256 + d0 + cl;
  #pragma unroll
  for (int i=0;i<4;i++) {
    float4 v = ((const float4*)s)[i];
    float a[4] = {v.x,v.y,v.z,v.w};
    #pragma unroll
    for (int j=0;j<4;j++) {
      ushort h = f2bf(a[j]); Th[rl][cl+4*i+j] = h; Tl[rl][cl+4*i+j] = f2bf(a[j] - bf2f(h));
    }
  }
  __syncthreads();
  const int dr = t>>2, mc = (t&3)*16;
  ushort oh[16] __attribute__((aligned(16)));
  ushort ol[16] __attribute__((aligned(16)));
  #pragma unroll
  for (int j=0;j<16;j++) { oh[j] = Th[mc+j][dr]; ol[j] = Tl[mc+j][dr]; }
  ushort* d2 = fT + (size_t)b*256*8192 + (size_t)(d0+dr)*8192 + m0 + mc;
  *(s8v*)d2 = *(s8v*)&oh[0]; *(s8v*)(d2+8) = *(s8v*)&oh[8];
  *(s8v*)(d2+4096) = *(s8v*)&ol[0]; *(s8v*)(d2+4104) = *(s8v*)&ol[8];
}

// W f32 [256][256] -> Ws [256][512] = [Wh | Wl]
__global__ __launch_bounds__(256)
void cvt_w_kernel(const float4* __restrict__ W, ushort* __restrict__ Ws)
{
  size_t i  = (size_t)blockIdx.x * 256 + threadIdx.x;
  size_t e0 = i * 4;
  int c = (int)(e0 & 255), r = (int)(e0 >> 8);
  float4 v = W[i];
  float a[4] = {v.x,v.y,v.z,v.w};
  ushort* hi = Ws + (size_t)r*512 + c;
  #pragma unroll
  for (int j=0;j<4;j++) { ushort h = f2bf(a[j]); hi[j] = h; hi[256+j] = f2bf(a[j]-bf2f(h)); }
}

// sum split-K AGG parts -> AGGcat bf16 [b*2048][512] = [Ah | Al]
__global__ __launch_bounds__(256)
void aggsum_kernel(const float* __restrict__ parts, long long kpC, int kparts,
                   ushort* __restrict__ AGGcat)
{
  const size_t i4 = (size_t)blockIdx.x*256 + threadIdx.x;  // 524288 float4s
  float4 sv = make_float4(0.f,0.f,0.f,0.f);
  for (int kp=0; kp<kparts; kp++) {
    float4 v = ((const float4*)(parts + (size_t)kp*kpC))[i4];
    sv.x+=v.x; sv.y+=v.y; sv.z+=v.z; sv.w+=v.w;
  }
  const size_t flat = i4*4;
  const size_t row = flat >> 8;
  const int d = (int)(flat & 255);
  float a[4] = {sv.x, sv.y, sv.z, sv.w};
  ushort4 hi, lo;
  { ushort h=f2bf(a[0]); hi.x=h; lo.x=f2bf(a[0]-bf2f(h)); }
  { ushort h=f2bf(a[1]); hi.y=h; lo.y=f2bf(a[1]-bf2f(h)); }
  { ushort h=f2bf(a[2]); hi.z=h; lo.z=f2bf(a[2]-bf2f(h)); }
  { ushort h=f2bf(a[3]); hi.w=h; lo.w=f2bf(a[3]-bf2f(h)); }
  ushort* dst = AGGcat + row*512 + d;
  *(ushort4*)dst = hi; *(ushort4*)(dst+256) = lo;
}

// ===================== softmax =====================
// per (b,d): max & 1/sum over e of ESt [b][256][2048] f32
__global__ __launch_bounds__(256)
void stats_kernel(const float* __restrict__ ESt, float2* __restrict__ stats)
{
  const int b = blockIdx.x >> 8, d = blockIdx.x & 255;
  const float* base = ESt + ((size_t)b*256 + d)*2048;
  const int t = threadIdx.x;
  const float4* p = (const float4*)base + t*2;
  float4 x = p[0], y = p[1];
  float v[8] = {x.x,x.y,x.z,x.w,y.x,y.y,y.z,y.w};
  float mx = v[0];
  #pragma unroll
  for (int j=1;j<8;j++) mx = fmaxf(mx, v[j]);
  #pragma unroll
  for (int off=32; off>=1; off>>=1) mx = fmaxf(mx, __shfl_down(mx, off));
  __shared__ float sm[8];
  const int lane = t & 63, w = t >> 6;
  if (lane==0) sm[w] = mx;
  __syncthreads();
  if (t==0) { sm[4] = fmaxf(fmaxf(sm[0],sm[1]),fmaxf(sm[2],sm[3])); }
  __syncthreads();
  mx = sm[4];
  float s = 0.f;
  #pragma unroll
  for (int j=0;j<8;j++) s += __expf(v[j]-mx);
  #pragma unroll
  for (int off=32; off>=1; off>>=1) s += __shfl_down(s, off);
  if (lane==0) sm[w] = s;
  __syncthreads();
  if (t==0) { float ss = sm[0]+sm[1]+sm[2]+sm[3]; stats[blockIdx.x] = make_float2(mx, 1.f/ss); }
}

// P[b][e][d] = exp(ES-mx)*inv * (Ah+Al)
__global__ __launch_bounds__(256)
void pmul_kernel(const float* __restrict__ ES, const ushort* __restrict__ AGGcat,
                 const float2* __restrict__ stats, ushort* __restrict__ P)
{
  const int b = blockIdx.x >> 6, e0 = (blockIdx.x & 63) * 32;
  const int t = threadIdx.x, tx = t & 63, ty = t >> 6;
  const int d4 = tx*4;
  const float2 st0 = stats[b*256+d4+0], st1 = stats[b*256+d4+1];
  const float2 st2 = stats[b*256+d4+2], st3 = stats[b*256+d4+3];
  for (int e = e0+ty; e < e0+32; e += 4) {
    const size_t ro = (size_t)b*2048 + e;
    float4 es = *(const float4*)(ES + ro*256 + d4);
    ushort4 ah = *(const ushort4*)(AGGcat + ro*512 + d4);
    ushort4 al = *(const ushort4*)(AGGcat + ro*512 + 256 + d4);
    ushort4 o;
    o.x = f2bf(__expf(es.x-st0.x)*st0.y*(bf2f(ah.x)+bf2f(al.x)));
    o.y = f2bf(__expf(es.y-st1.x)*st1.y*(bf2f(ah.y)+bf2f(al.y)));
    o.z = f2bf(__expf(es.z-st2.x)*st2.y*(bf2f(ah.z)+bf2f(al.z)));
    o.w = f2bf(__expf(es.w-st3.x)*st3.y*(bf2f(ah.w)+bf2f(al.w)));
    *(ushort4*)(P + ro*256 + d4) = o;
  }
}

__global__ __launch_bounds__(256)
void inc_copy_kernel(const float4* __restrict__ src, float4* __restrict__ dst, size_t n4)
{
  size_t i = (size_t)blockIdx.x*256 + threadIdx.x;
  const size_t stride = (size_t)gridDim.x*256;
  for (; i < n4; i += stride) dst[i] = src[i];
}

// ===================== host =====================
extern "C" void kernel_launch(void* const* d_in, const int* in_sizes, int n_in,
                              void* d_out, int out_size, void* d_ws, size_t ws_size,
                              hipStream_t stream) {
  const float* feat    = (const float*)d_in[0];
  const float* inc     = (const float*)d_in[1];
  const float* vcWatt  = (const float*)d_in[2];
  const float* vcWproj = (const float*)d_in[3];
  // d_in[4] vc_alpha: unused (edge_feats == ef_base every layer); d_in[5] ec_W_att: dead code
  const float* ecWproj = (const float*)d_in[6];
  const float* ecAlpha = (const float*)d_in[7];
  const int*   nLayers = (const int*)d_in[8];

  const int Bb=4, Mm=4096, E=2048, D=256;
  const size_t nodeN = (size_t)Bb*Mm*D, edgeN = (size_t)Bb*E*D, incN = (size_t)Bb*Mm*E;

  const int kparts = 8;
  const size_t fTB    = (size_t)Bb*256*8192*2;   // 16.78 MB
  const size_t partsB = (size_t)kparts*Bb*E*D*4; // 67.1 MB
  const size_t AGGcatB= (size_t)Bb*E*512*2;      // 8.39 MB
  const size_t ESB    = (size_t)Bb*E*D*4;        // 8.39 MB
  const size_t EStB   = ESB;                     // 8.39 MB
  const size_t PB     = edgeN*2;                 // 4.19 MB
  const size_t ebfB   = edgeN*2;                 // 4.19 MB
  const size_t E2TB   = edgeN*2;                 // 4.19 MB
  const size_t WsB    = (size_t)3*256*512*2;
  const size_t statB  = (size_t)Bb*256*sizeof(float2);
  const size_t incTB  = incN*2, incbfB = incN*2; // 67.1 MB each
  const size_t needB  = fTB+partsB+AGGcatB+ESB+EStB+PB+ebfB+E2TB+WsB+statB;
  const bool planA = ws_size >= needB + incTB + incbfB;

  char* ws = (char*)d_ws;
  ushort* fT    = (ushort*)ws;  ws += fTB;
  float*  parts = (float*)ws;   ws += partsB;
  ushort* AGGcat= (ushort*)ws;  ws += AGGcatB;
  float*  ES    = (float*)ws;   ws += ESB;
  float*  ESt   = (float*)ws;   ws += EStB;
  ushort* P     = (ushort*)ws;  ws += PB;
  ushort* edgebf= (ushort*)ws;  ws += ebfB;
  ushort* E2T   = (ushort*)ws;  ws += E2TB;
  ushort* Ws0   = (ushort*)ws;            // vc_W_att
  ushort* Ws1   = Ws0 + 256*512;          // vc_W_proj
  ushort* Ws2   = Ws1 + 256*512;          // ec_W_proj
  ws += WsB;
  float2* stats = (float2*)ws;  ws += statB;

  float* outNode = (float*)d_out;
  float* outEdge = outNode + nodeN;
  float* outInc  = outEdge + edgeN;
  ushort *incT, *incbf;
  if (planA) { incT = (ushort*)ws; incbf = incT + incN; }
  else       { incT = (ushort*)outInc; incbf = incT + incN; }  // scratch in outInc region (134.2 MB), fixed by final copy

  const long long kpC = (long long)Bb*E*D;  // part stride (floats)
  dim3 blk(256);

  // 0. weight splits + input transposes
  cvt_w_kernel<<<dim3(64), blk, 0, stream>>>((const float4*)vcWatt,  Ws0);
  cvt_w_kernel<<<dim3(64), blk, 0, stream>>>((const float4*)vcWproj, Ws1);
  cvt_w_kernel<<<dim3(64), blk, 0, stream>>>((const float4*)ecWproj, Ws2);
  trans_feat_kernel<<<dim3(64,4,4), blk, 0, stream>>>(feat, fT);
  trans_inc_kernel<<<dim3(64,32,4), blk, 0, stream>>>(inc, outInc, planA ? 1 : 0, incbf, incT);

  // 1. AGG parts = incT @ fT^T   (K=8192: fh then fl, inc wraps; split-K)
  gemm_kernel<1,0,0,4,0><<<dim3(2,16,4*kparts), blk, 0, stream>>>(
      incT, 4096, (long long)E*4096, fT, 8192, (long long)256*8192,
      parts, nullptr, D, (long long)E*D, 0, 0, kpC, 8192/kparts, kparts,
      nullptr, nullptr, nullptr);

  // 2. sum parts -> AGGcat [e][512] = [Ah|Al]
  aggsum_kernel<<<dim3(2048), blk, 0, stream>>>(parts, kpC, kparts, AGGcat);

  // 3. ES = AGG @ vcWatt^T  (4-term hi/lo, K=1024) -> f32 [e][256] + transposed [256][2048]
  gemm_kernel<5,3,6,2,0><<<dim3(4,32,4), blk, 0, stream>>>(
      AGGcat, 512, (long long)E*512, Ws0, 512, 0,
      ES, ESt, D, (long long)E*D, E, (long long)D*E, 0, 1024, 1,
      nullptr, nullptr, nullptr);

  // 4. softmax stats + P
  stats_kernel<<<dim3(Bb*256), blk, 0, stream>>>(ESt, stats);
  pmul_kernel<<<dim3(Bb*64), blk, 0, stream>>>(ES, AGGcat, stats, P);

  // 5. edge_out = P @ vcWproj^T (K=512 hi/lo) -> f32 out + straight bf16 edgebf
  gemm_kernel<4,3,3,2,0><<<dim3(4,32,4), blk, 0, stream>>>(
      P, 256, (long long)E*D, Ws1, 512, 0,
      outEdge, edgebf, D, (long long)E*D, 0, 0, 0, 512, 1,
      nullptr, nullptr, nullptr);

  // 6. E2 = edge_out @ ecWproj^T (K=512 dup/hi-lo) -> bf16 transposed E2T [256][2048]
  //    (associativity: (inc@edge)@W2^T == inc@(edge@W2^T))
  gemm_kernel<4,3,8,2,0><<<dim3(4,32,4), blk, 0, stream>>>(
      edgebf, 256, (long long)E*D, Ws2, 512, 0,
      nullptr, E2T, D, (long long)E*D, E, (long long)D*E, 0, 512, 1,
      nullptr, nullptr, nullptr);

  // 7. node_out = a^L*feat + (1-a^L)*(incbf @ E2T^T)  (K=2048; GORD=1 streams A once)
  gemm_kernel<0,0,2,2,1><<<dim3(64,4,4), blk, 0, stream>>>(
      incbf, 2048, (long long)Mm*E, E2T, 2048, (long long)D*E,
      outNode, nullptr, D, (long long)Mm*D, 0, 0, 0, 2048, 1,
      feat, ecAlpha, nLayers);

  // 8. plan B: restore inc passthrough (overwrites incT/incbf scratch)
  if (!planA)
    inc_copy_kernel<<<dim3(2048), blk, 0, stream>>>((const float4*)inc, (float4*)outInc, incN/4);
}